// Round 1
// baseline (1291.684 us; speedup 1.0000x reference)
//
#include <hip/hip_runtime.h>
#include <hip/hip_bf16.h>
#include <stdint.h>

// Problem constants (from reference)
#define V_SZ 32000
#define D_SZ 1024          // = K
#define M_SZ 8192          // B*S = 4*2048

typedef __attribute__((ext_vector_type(8))) short bf16x8;
typedef __attribute__((ext_vector_type(4))) float f32x4;

static __device__ __forceinline__ unsigned short f32_to_bf16_rne(float f) {
    union { float f; uint32_t u; } v; v.f = f;
    uint32_t u = v.u;
    uint32_t lsb = (u >> 16) & 1;
    u += 0x7fffu + lsb;
    return (unsigned short)(u >> 16);
}

// ---------------------------------------------------------------------------
// Kernel 1: embedding gather. One block per output row, float4 copy.
__global__ void gather_rows(const int* __restrict__ ids,
                            const float* __restrict__ table,
                            float* __restrict__ out) {
    int row = blockIdx.x;
    int id  = ids[row];
    const float4* src = (const float4*)(table + (size_t)id * D_SZ);
    float4*       dst = (float4*)(out + (size_t)row * D_SZ);
    dst[threadIdx.x] = src[threadIdx.x];   // blockDim.x == 256 == D/4
}

// ---------------------------------------------------------------------------
// Kernel 2: cast embeds f32 -> bf16 (A matrix [M][K]), 8 elems/thread.
__global__ void cast_f32_bf16(const float* __restrict__ in,
                              unsigned short* __restrict__ out, int n8) {
    int i = blockIdx.x * blockDim.x + threadIdx.x;
    int stride = gridDim.x * blockDim.x;
    for (; i < n8; i += stride) {
        const float4* p = (const float4*)(in + (size_t)i * 8);
        float4 a = p[0], b = p[1];
        union { unsigned short s[8]; uint4 v; } r;
        r.s[0] = f32_to_bf16_rne(a.x); r.s[1] = f32_to_bf16_rne(a.y);
        r.s[2] = f32_to_bf16_rne(a.z); r.s[3] = f32_to_bf16_rne(a.w);
        r.s[4] = f32_to_bf16_rne(b.x); r.s[5] = f32_to_bf16_rne(b.y);
        r.s[6] = f32_to_bf16_rne(b.z); r.s[7] = f32_to_bf16_rne(b.w);
        ((uint4*)out)[i] = r.v;
    }
}

// ---------------------------------------------------------------------------
// Kernel 3: transpose+cast out_weight [K=1024][V=32000] f32 -> Bt [V][K] bf16.
// 32x32 tiles via LDS (row padded to 34 to kill bank conflicts).
__global__ void transpose_cast(const float* __restrict__ w,
                               unsigned short* __restrict__ bt) {
    __shared__ unsigned short tile[32][34];
    int n0 = blockIdx.x * 32;          // column block in V
    int k0 = blockIdx.y * 32;          // row block in K
    int r = threadIdx.x >> 5;          // 0..7
    int c = threadIdx.x & 31;          // 0..31
#pragma unroll
    for (int rr = 0; rr < 32; rr += 8) {
        float v = w[(size_t)(k0 + r + rr) * V_SZ + (n0 + c)];
        tile[c][r + rr] = f32_to_bf16_rne(v);
    }
    __syncthreads();
    int nl = threadIdx.x >> 3;         // 0..31
    int ks = threadIdx.x & 7;          // 0..7  (4 bf16 = 8B per thread)
    union { unsigned short s[4]; uint2 v; } r2;
#pragma unroll
    for (int j = 0; j < 4; ++j) r2.s[j] = tile[nl][ks * 4 + j];
    ((uint2*)(bt + (size_t)(n0 + nl) * D_SZ + k0))[ks] = r2.v;
}

// ---------------------------------------------------------------------------
// Kernel 4: bf16 GEMM  C[M][N] = A[M][K] * Bt[N][K]^T, f32 accumulate.
// 128x128 tile, BK=32, 4 waves (2x2), 16x16x32 MFMA, 4x4 frags/wave.
// LDS layout [hi][row][8] (k-split) -> ds_read_b128 fragments are 2-way max.
#define BM 128
#define BN 128
#define BK 32
#define KTILES (D_SZ / BK)   // 32

static __device__ __forceinline__ void gload_lds16(const unsigned short* g, void* lds) {
    __builtin_amdgcn_global_load_lds(
        (const __attribute__((address_space(1))) void*)g,
        (__attribute__((address_space(3))) void*)lds,
        16, 0, 0);
}

__global__ __launch_bounds__(256)
void gemm_bf16(const unsigned short* __restrict__ A,
               const unsigned short* __restrict__ Bt,
               float* __restrict__ C) {
    // Asm[hi][row][j] = A[bm0+row][k0 + hi*8 + j]
    __shared__ unsigned short Asm[4][BM][8];   // 8 KB
    __shared__ unsigned short Bsm[4][BN][8];   // 8 KB

    const int tid  = threadIdx.x;
    const int lane = tid & 63;
    const int w    = tid >> 6;           // wave 0..3
    const int wr   = w >> 1;             // wave row (m)  0..1
    const int wc   = w & 1;              // wave col (n)  0..1

    const int bn0 = blockIdx.x * BN;
    const int bm0 = blockIdx.y * BM;

    // Staging: wave w fills hi-group w. chunk0: rows [0,64), chunk1: rows [64,128)
    const unsigned short* pA0 = A  + (size_t)(bm0 + lane)      * D_SZ + w * 8;
    const unsigned short* pA1 = A  + (size_t)(bm0 + 64 + lane) * D_SZ + w * 8;
    const unsigned short* pB0 = Bt + (size_t)(bn0 + lane)      * D_SZ + w * 8;
    const unsigned short* pB1 = Bt + (size_t)(bn0 + 64 + lane) * D_SZ + w * 8;
    char* ldsA0 = (char*)Asm + w * 2048;
    char* ldsA1 = (char*)Asm + w * 2048 + 1024;
    char* ldsB0 = (char*)Bsm + w * 2048;
    char* ldsB1 = (char*)Bsm + w * 2048 + 1024;

    f32x4 acc[4][4];
#pragma unroll
    for (int m = 0; m < 4; ++m)
#pragma unroll
        for (int n = 0; n < 4; ++n)
#pragma unroll
            for (int e = 0; e < 4; ++e) acc[m][n][e] = 0.0f;

    const int frow = lane & 15;
    const int fhi  = lane >> 4;

    for (int kt = 0; kt < KTILES; ++kt) {
        // stage next K-slab into LDS (direct HBM->LDS, 16B/lane)
        gload_lds16(pA0, ldsA0);
        gload_lds16(pA1, ldsA1);
        gload_lds16(pB0, ldsB0);
        gload_lds16(pB1, ldsB1);
        pA0 += BK; pA1 += BK; pB0 += BK; pB1 += BK;
        __syncthreads();   // compiler drains vmcnt before barrier

        bf16x8 af[4], bfr[4];
#pragma unroll
        for (int m = 0; m < 4; ++m)
            af[m] = *(const bf16x8*)&Asm[fhi][wr * 64 + m * 16 + frow][0];
#pragma unroll
        for (int n = 0; n < 4; ++n)
            bfr[n] = *(const bf16x8*)&Bsm[fhi][wc * 64 + n * 16 + frow][0];

#pragma unroll
        for (int m = 0; m < 4; ++m)
#pragma unroll
            for (int n = 0; n < 4; ++n)
                acc[m][n] = __builtin_amdgcn_mfma_f32_16x16x32_bf16(
                    af[m], bfr[n], acc[m][n], 0, 0, 0);

        __syncthreads();   // before overwriting LDS next iter
    }

    // C write: row = (lane>>4)*4 + e, col = lane&15 within each 16x16 frag
    const int crow0 = bm0 + wr * 64 + (lane >> 4) * 4;
    const int ccol0 = bn0 + wc * 64 + (lane & 15);
#pragma unroll
    for (int m = 0; m < 4; ++m)
#pragma unroll
        for (int n = 0; n < 4; ++n) {
            float* cp = C + (size_t)(crow0 + m * 16) * V_SZ + (ccol0 + n * 16);
#pragma unroll
            for (int e = 0; e < 4; ++e)
                cp[(size_t)e * V_SZ] = acc[m][n][e];
        }
}

// ---------------------------------------------------------------------------
extern "C" void kernel_launch(void* const* d_in, const int* in_sizes, int n_in,
                              void* d_out, int out_size, void* d_ws, size_t ws_size,
                              hipStream_t stream) {
    const int*   ids        = (const int*)d_in[0];       // [B,S] = 8192
    const float* embeds     = (const float*)d_in[1];     // [B,S,D]
    const float* in_weight  = (const float*)d_in[2];     // [V,D]
    const float* out_weight = (const float*)d_in[3];     // [D,V]

    float* out_embedded = (float*)d_out;                       // M*D floats
    float* out_logits   = (float*)d_out + (size_t)M_SZ * D_SZ; // M*V floats

    // workspace: A bf16 [M][K] (16 MB) + Bt bf16 [V][K] (64 MB) = ~82 MB
    unsigned short* Abf  = (unsigned short*)d_ws;
    unsigned short* Btbf = Abf + (size_t)M_SZ * D_SZ;

    gather_rows<<<M_SZ, 256, 0, stream>>>(ids, in_weight, out_embedded);
    cast_f32_bf16<<<2048, 256, 0, stream>>>(embeds, Abf, M_SZ * D_SZ / 8);
    transpose_cast<<<dim3(V_SZ / 32, D_SZ / 32), 256, 0, stream>>>(out_weight, Btbf);
    gemm_bf16<<<dim3(V_SZ / BN, M_SZ / BM), 256, 0, stream>>>(Abf, Btbf, out_logits);
}

// Round 2
// 871.675 us; speedup vs baseline: 1.4818x; 1.4818x over previous
//
#include <hip/hip_runtime.h>
#include <hip/hip_bf16.h>
#include <stdint.h>

// Problem constants (from reference)
#define V_SZ 32000
#define D_SZ 1024          // = K
#define M_SZ 8192          // B*S = 4*2048

typedef __attribute__((ext_vector_type(8))) short bf16x8;
typedef __attribute__((ext_vector_type(4))) float f32x4;

static __device__ __forceinline__ unsigned short f32_to_bf16_rne(float f) {
    union { float f; uint32_t u; } v; v.f = f;
    uint32_t u = v.u;
    uint32_t lsb = (u >> 16) & 1;
    u += 0x7fffu + lsb;
    return (unsigned short)(u >> 16);
}

// ---------------------------------------------------------------------------
// Kernel 1: embedding gather. One block per output row, float4 copy.
__global__ void gather_rows(const int* __restrict__ ids,
                            const float* __restrict__ table,
                            float* __restrict__ out) {
    int row = blockIdx.x;
    int id  = ids[row];
    const float4* src = (const float4*)(table + (size_t)id * D_SZ);
    float4*       dst = (float4*)(out + (size_t)row * D_SZ);
    dst[threadIdx.x] = src[threadIdx.x];   // blockDim.x == 256 == D/4
}

// ---------------------------------------------------------------------------
// Kernel 2: cast embeds f32 -> bf16 (A matrix [M][K]), 8 elems/thread.
__global__ void cast_f32_bf16(const float* __restrict__ in,
                              unsigned short* __restrict__ out, int n8) {
    int i = blockIdx.x * blockDim.x + threadIdx.x;
    int stride = gridDim.x * blockDim.x;
    for (; i < n8; i += stride) {
        const float4* p = (const float4*)(in + (size_t)i * 8);
        float4 a = p[0], b = p[1];
        union { unsigned short s[8]; uint4 v; } r;
        r.s[0] = f32_to_bf16_rne(a.x); r.s[1] = f32_to_bf16_rne(a.y);
        r.s[2] = f32_to_bf16_rne(a.z); r.s[3] = f32_to_bf16_rne(a.w);
        r.s[4] = f32_to_bf16_rne(b.x); r.s[5] = f32_to_bf16_rne(b.y);
        r.s[6] = f32_to_bf16_rne(b.z); r.s[7] = f32_to_bf16_rne(b.w);
        ((uint4*)out)[i] = r.v;
    }
}

// ---------------------------------------------------------------------------
// Kernel 3: transpose+cast out_weight [K=1024][V=32000] f32 -> Bt [V][K] bf16.
__global__ void transpose_cast(const float* __restrict__ w,
                               unsigned short* __restrict__ bt) {
    __shared__ unsigned short tile[32][34];
    int n0 = blockIdx.x * 32;          // column block in V
    int k0 = blockIdx.y * 32;          // row block in K
    int r = threadIdx.x >> 5;          // 0..7
    int c = threadIdx.x & 31;          // 0..31
#pragma unroll
    for (int rr = 0; rr < 32; rr += 8) {
        float v = w[(size_t)(k0 + r + rr) * V_SZ + (n0 + c)];
        tile[c][r + rr] = f32_to_bf16_rne(v);
    }
    __syncthreads();
    int nl = threadIdx.x >> 3;         // 0..31
    int ks = threadIdx.x & 7;          // 0..7  (4 bf16 = 8B per thread)
    union { unsigned short s[4]; uint2 v; } r2;
#pragma unroll
    for (int j = 0; j < 4; ++j) r2.s[j] = tile[nl][ks * 4 + j];
    ((uint2*)(bt + (size_t)(n0 + nl) * D_SZ + k0))[ks] = r2.v;
}

// ---------------------------------------------------------------------------
// Kernel 4: bf16 GEMM, 256x256 tile, BK=64, 8 waves (2Mx4N), 8-phase schedule.
// LDS 128 KiB: [dbuf][A|B][half]  each half-tile = [8 hi][128 row][8 bf16] = 16KB
// (k-split layout: measured 0 bank conflicts in round 1; linear in
//  global_load_lds staging order so no swizzle needed.)
#define BM 256
#define BN 256
#define BK 64
#define NT (D_SZ / BK)   // 16

static __device__ __forceinline__ void gload_lds16(const unsigned short* g, void* lds) {
    __builtin_amdgcn_global_load_lds(
        (const __attribute__((address_space(1))) void*)g,
        (__attribute__((address_space(3))) void*)lds,
        16, 0, 0);
}

// one half-tile stage: 2 x global_load_lds(16B) per thread (512 threads * 32B = 16KB)
static __device__ __forceinline__ void stage_half(const unsigned short* g, char* slot,
                                                  int hi0, int row0) {
    gload_lds16(g,      slot + hi0 * 2048 + row0 * 16);
    gload_lds16(g + 32, slot + (hi0 + 4) * 2048 + row0 * 16);
}

__global__ __launch_bounds__(512, 2)
void gemm_bf16_8p(const unsigned short* __restrict__ A,
                  const unsigned short* __restrict__ Bt,
                  float* __restrict__ C) {
    __shared__ __align__(16) char lds[131072];

    const int tid  = threadIdx.x;
    const int lane = tid & 63;
    const int w    = tid >> 6;           // wave 0..7
    const int wr   = w >> 2;             // 0..1  (A half)
    const int wc   = w & 3;              // 0..3  (B: half = wc>>1, sub = wc&1)

    // XCD-aware swizzle (grid = 4000, 4000 % 8 == 0 -> simple variant is bijective)
    const int nwg = gridDim.x;
    const int cpx = nwg >> 3;            // 500
    const int bid = blockIdx.x;
    const int swz = (bid & 7) * cpx + (bid >> 3);
    const int bm0 = (swz & 31) * BM;     // 32 M-tiles, fastest -> share B panel
    const int bn0 = (swz >> 5) * BN;     // 125 N-tiles

    // staging thread mapping: covers (hi0, row0) and (hi0+4, row0)
    const int hi0  = tid >> 7;           // 0..3
    const int row0 = tid & 127;          // 0..127
    const unsigned short* gA = A  + (size_t)(bm0 + row0) * D_SZ + hi0 * 8;
    const unsigned short* gB = Bt + (size_t)(bn0 + row0) * D_SZ + hi0 * 8;

#define STAGE_A(tt, h) stage_half(gA + (size_t)(h) * 128 * D_SZ + (tt) * 64, \
                                  (char*)lds + ((tt) & 1) * 65536 + (h) * 16384, hi0, row0)
#define STAGE_B(tt, h) stage_half(gB + (size_t)(h) * 128 * D_SZ + (tt) * 64, \
                                  (char*)lds + ((tt) & 1) * 65536 + 32768 + (h) * 16384, hi0, row0)

    f32x4 acc[8][4];
#pragma unroll
    for (int m = 0; m < 8; ++m)
#pragma unroll
        for (int n = 0; n < 4; ++n)
#pragma unroll
            for (int e = 0; e < 4; ++e) acc[m][n][e] = 0.0f;

    bf16x8 a[4][2];        // current qm quadrant A frags
    bf16x8 b[2][2][2];     // [qn][ni][kk] B frags (both qn kept live)

    const int frow = lane & 15;
    const int fhi  = lane >> 4;

    // frag read: addr = (kk*4+fhi)*2048 + row_local*16
#define LDA(mi, kk, QM) (*(const bf16x8*)(abuf + ((kk) * 4 + fhi) * 2048 + \
                         ((QM) * 64 + (mi) * 16 + frow) * 16))
#define LDB(ni, kk, QN) (*(const bf16x8*)(bbuf + ((kk) * 4 + fhi) * 2048 + \
                         (((QN) * 2 + (ni)) * 16 + frow) * 16))
#define READ_A(QM) \
    _Pragma("unroll") for (int mi = 0; mi < 4; ++mi) { \
        a[mi][0] = LDA(mi, 0, QM); a[mi][1] = LDA(mi, 1, QM); }
#define READ_B(QN) \
    _Pragma("unroll") for (int ni = 0; ni < 2; ++ni) { \
        b[QN][ni][0] = LDB(ni, 0, QN); b[QN][ni][1] = LDB(ni, 1, QN); }
#define MFMA_Q(QM, QN) \
    __builtin_amdgcn_s_setprio(1); \
    _Pragma("unroll") for (int mi = 0; mi < 4; ++mi) \
    _Pragma("unroll") for (int ni = 0; ni < 2; ++ni) \
    _Pragma("unroll") for (int kk = 0; kk < 2; ++kk) \
        acc[(QM) * 4 + mi][(QN) * 2 + ni] = __builtin_amdgcn_mfma_f32_16x16x32_bf16( \
            a[mi][kk], b[QN][ni][kk], acc[(QM) * 4 + mi][(QN) * 2 + ni], 0, 0, 0); \
    __builtin_amdgcn_s_setprio(0);
#define MIDSYNC \
    __builtin_amdgcn_sched_barrier(0); \
    __builtin_amdgcn_s_barrier(); \
    asm volatile("s_waitcnt lgkmcnt(0)" ::: "memory"); \
    __builtin_amdgcn_sched_barrier(0);

    // Prologue: tile 0 fully + tile 1 minus HA1(1); wait oldest 8 (= tile 0).
    STAGE_B(0, 0); STAGE_B(0, 1); STAGE_A(0, 0); STAGE_A(0, 1);
    STAGE_B(1, 0); STAGE_B(1, 1); STAGE_A(1, 0);
    asm volatile("s_waitcnt vmcnt(6)" ::: "memory");
    __builtin_amdgcn_s_barrier();

    for (int t = 0; t < NT; ++t) {
        const char* abuf = (const char*)lds + (t & 1) * 65536 + wr * 16384;
        const char* bbuf = (const char*)lds + (t & 1) * 65536 + 32768
                           + (wc >> 1) * 16384 + (wc & 1) * 1024;

        // ---- Phase 0: quadrant (0,0); stage HA1(t+1) (slot free since P2(t-1))
        READ_A(0); READ_B(0);
        if (t + 1 < NT) STAGE_A(t + 1, 1);
        MIDSYNC;
        MFMA_Q(0, 0);
        __builtin_amdgcn_s_barrier();

        // ---- Phase 1: quadrant (0,1)
        READ_B(1);
        MIDSYNC;
        MFMA_Q(0, 1);
        __builtin_amdgcn_s_barrier();

        // ---- Phase 2: quadrant (1,1); stage HB0(t+2) (HB slots free after P1)
        READ_A(1);
        if (t + 2 < NT) STAGE_B(t + 2, 0);
        MIDSYNC;
        MFMA_Q(1, 1);
        __builtin_amdgcn_s_barrier();

        // ---- Phase 3: quadrant (1,0); stage HB1(t+2), HA0(t+2) (HA free after P2)
        if (t + 2 < NT) { STAGE_B(t + 2, 1); STAGE_A(t + 2, 0); }
        MIDSYNC;
        MFMA_Q(1, 0);
        // counted wait: guarantee tile t+1 fully landed (3 half-tiles in flight)
        if (t < NT - 2)       { asm volatile("s_waitcnt vmcnt(6)" ::: "memory"); }
        else if (t == NT - 2) { asm volatile("s_waitcnt vmcnt(0)" ::: "memory"); }
        __builtin_amdgcn_s_barrier();
    }

    // Epilogue: C write. row = base + (lane>>4)*4 + e, col = base + (lane&15)
    const int crow = bm0 + wr * 128 + (lane >> 4) * 4;
    const int ccol = bn0 + wc * 64 + (lane & 15);
#pragma unroll
    for (int mi = 0; mi < 8; ++mi)
#pragma unroll
        for (int ni = 0; ni < 4; ++ni) {
            float* cp = C + (size_t)(crow + mi * 16) * V_SZ + (ccol + ni * 16);
#pragma unroll
            for (int e = 0; e < 4; ++e)
                cp[(size_t)e * V_SZ] = acc[mi][ni][e];
        }
#undef STAGE_A
#undef STAGE_B
#undef LDA
#undef LDB
#undef READ_A
#undef READ_B
#undef MFMA_Q
#undef MIDSYNC
}

// ---------------------------------------------------------------------------
extern "C" void kernel_launch(void* const* d_in, const int* in_sizes, int n_in,
                              void* d_out, int out_size, void* d_ws, size_t ws_size,
                              hipStream_t stream) {
    const int*   ids        = (const int*)d_in[0];       // [B,S] = 8192
    const float* embeds     = (const float*)d_in[1];     // [B,S,D]
    const float* in_weight  = (const float*)d_in[2];     // [V,D]
    const float* out_weight = (const float*)d_in[3];     // [D,V]

    float* out_embedded = (float*)d_out;                       // M*D floats
    float* out_logits   = (float*)d_out + (size_t)M_SZ * D_SZ; // M*V floats

    // workspace: A bf16 [M][K] (16 MB) + Bt bf16 [V][K] (64 MB) = ~82 MB
    unsigned short* Abf  = (unsigned short*)d_ws;
    unsigned short* Btbf = Abf + (size_t)M_SZ * D_SZ;

    gather_rows<<<M_SZ, 256, 0, stream>>>(ids, in_weight, out_embedded);
    cast_f32_bf16<<<2048, 256, 0, stream>>>(embeds, Abf, M_SZ * D_SZ / 8);
    transpose_cast<<<dim3(V_SZ / 32, D_SZ / 32), 256, 0, stream>>>(out_weight, Btbf);
    gemm_bf16_8p<<<dim3((V_SZ / BN) * (M_SZ / BM)), 512, 0, stream>>>(Abf, Btbf, out_logits);
}

// Round 3
// 858.101 us; speedup vs baseline: 1.5053x; 1.0158x over previous
//
#include <hip/hip_runtime.h>
#include <hip/hip_bf16.h>
#include <stdint.h>

// Problem constants (from reference)
#define V_SZ 32000
#define D_SZ 1024          // = K
#define M_SZ 8192          // B*S = 4*2048

typedef __attribute__((ext_vector_type(8))) short bf16x8;
typedef __attribute__((ext_vector_type(4))) float f32x4;

static __device__ __forceinline__ unsigned short f32_to_bf16_rne(float f) {
    union { float f; uint32_t u; } v; v.f = f;
    uint32_t u = v.u;
    uint32_t lsb = (u >> 16) & 1;
    u += 0x7fffu + lsb;
    return (unsigned short)(u >> 16);
}

// ---------------------------------------------------------------------------
// Kernel 1: embedding gather. One block per output row, float4 copy.
__global__ void gather_rows(const int* __restrict__ ids,
                            const float* __restrict__ table,
                            float* __restrict__ out) {
    int row = blockIdx.x;
    int id  = ids[row];
    const float4* src = (const float4*)(table + (size_t)id * D_SZ);
    float4*       dst = (float4*)(out + (size_t)row * D_SZ);
    dst[threadIdx.x] = src[threadIdx.x];   // blockDim.x == 256 == D/4
}

// ---------------------------------------------------------------------------
// Kernel 2: cast embeds f32 -> bf16 (A matrix [M][K]), 8 elems/thread.
__global__ void cast_f32_bf16(const float* __restrict__ in,
                              unsigned short* __restrict__ out, int n8) {
    int i = blockIdx.x * blockDim.x + threadIdx.x;
    int stride = gridDim.x * blockDim.x;
    for (; i < n8; i += stride) {
        const float4* p = (const float4*)(in + (size_t)i * 8);
        float4 a = p[0], b = p[1];
        union { unsigned short s[8]; uint4 v; } r;
        r.s[0] = f32_to_bf16_rne(a.x); r.s[1] = f32_to_bf16_rne(a.y);
        r.s[2] = f32_to_bf16_rne(a.z); r.s[3] = f32_to_bf16_rne(a.w);
        r.s[4] = f32_to_bf16_rne(b.x); r.s[5] = f32_to_bf16_rne(b.y);
        r.s[6] = f32_to_bf16_rne(b.z); r.s[7] = f32_to_bf16_rne(b.w);
        ((uint4*)out)[i] = r.v;
    }
}

// ---------------------------------------------------------------------------
// Kernel 3: transpose+cast out_weight [K=1024][V=32000] f32 -> Bt [V][K] bf16.
__global__ void transpose_cast(const float* __restrict__ w,
                               unsigned short* __restrict__ bt) {
    __shared__ unsigned short tile[32][34];
    int n0 = blockIdx.x * 32;          // column block in V
    int k0 = blockIdx.y * 32;          // row block in K
    int r = threadIdx.x >> 5;          // 0..7
    int c = threadIdx.x & 31;          // 0..31
#pragma unroll
    for (int rr = 0; rr < 32; rr += 8) {
        float v = w[(size_t)(k0 + r + rr) * V_SZ + (n0 + c)];
        tile[c][r + rr] = f32_to_bf16_rne(v);
    }
    __syncthreads();
    int nl = threadIdx.x >> 3;         // 0..31
    int ks = threadIdx.x & 7;          // 0..7  (4 bf16 = 8B per thread)
    union { unsigned short s[4]; uint2 v; } r2;
#pragma unroll
    for (int j = 0; j < 4; ++j) r2.s[j] = tile[nl][ks * 4 + j];
    ((uint2*)(bt + (size_t)(n0 + nl) * D_SZ + k0))[ks] = r2.v;
}

// ---------------------------------------------------------------------------
// Kernel 4: bf16 GEMM, 256x256 tile, BK=64, 8 waves (2Mx4N), 4-phase/K-tile.
// LDS 128 KiB: [dbuf][A|B][half]  half-tile = [8 hi][128 row][8 bf16] = 16KB.
// k-split layout: 0 bank conflicts (round 1/2 measured), linear in
// global_load_lds order. No manual lgkm drains: ds_reads are compiler-visible,
// hipcc inserts fine-grained counted lgkmcnt between ds_read and MFMA.
#define BM 256
#define BN 256
#define BK 64
#define NT (D_SZ / BK)   // 16

static __device__ __forceinline__ void gload_lds16(const unsigned short* g, void* lds) {
    __builtin_amdgcn_global_load_lds(
        (const __attribute__((address_space(1))) void*)g,
        (__attribute__((address_space(3))) void*)lds,
        16, 0, 0);
}

__global__ __launch_bounds__(512, 2)
void gemm_bf16_8p(const unsigned short* __restrict__ A,
                  const unsigned short* __restrict__ Bt,
                  float* __restrict__ C) {
    __shared__ __align__(16) char lds[131072];

    const int tid  = threadIdx.x;
    const int lane = tid & 63;
    const int w    = tid >> 6;           // wave 0..7
    const int wr   = w >> 2;             // 0..1  (A half)
    const int wc   = w & 3;              // 0..3  (B: half = wc>>1, sub = wc&1)

    // XCD-aware swizzle (grid = 4000, %8==0 -> simple variant bijective)
    const int nwg = gridDim.x;
    const int cpx = nwg >> 3;            // 500
    const int bid = blockIdx.x;
    const int swz = (bid & 7) * cpx + (bid >> 3);
    const int bm0 = (swz & 31) * BM;     // bm fastest -> same-XCD blocks share B panel
    const int bn0 = (swz >> 5) * BN;

    // staging thread mapping: (hi0,row0) and (hi0+4,row0)
    const int hi0  = tid >> 7;           // 0..3
    const int row0 = tid & 127;          // 0..127
    const int dstO = hi0 * 2048 + row0 * 16;
    const unsigned short* gA = A  + (size_t)(bm0 + row0) * D_SZ + hi0 * 8;
    const unsigned short* gB = Bt + (size_t)(bn0 + row0) * D_SZ + hi0 * 8;

    // 2 x 16B direct-to-LDS per stage-half (512 thr * 32B = 16 KB)
#define STG(ptr, slotbase) do { \
    gload_lds16((ptr),      (char*)lds + (slotbase) + dstO); \
    gload_lds16((ptr) + 32, (char*)lds + (slotbase) + dstO + 8192); } while (0)

    // Prologue: tile 0 fully + tile 1 minus A1(1); wait oldest 8 (= tile 0).
    STG(gB,                           32768);
    STG(gB + (size_t)128 * D_SZ,      32768 + 16384);
    STG(gA,                           0);
    STG(gA + (size_t)128 * D_SZ,      16384);
    STG(gB + 64,                      65536 + 32768);
    STG(gB + (size_t)128 * D_SZ + 64, 65536 + 32768 + 16384);
    STG(gA + 64,                      65536);
    asm volatile("s_waitcnt vmcnt(6)" ::: "memory");
    __builtin_amdgcn_s_barrier();

    // running staging pointers (strength-reduced): A1 at tile t+1; rest at t+2
    const unsigned short* pA1 = gA + (size_t)128 * D_SZ + 64;
    const unsigned short* pB0 = gB + 128;
    const unsigned short* pB1 = gB + (size_t)128 * D_SZ + 128;
    const unsigned short* pA0 = gA + 128;

    f32x4 acc[8][4];
#pragma unroll
    for (int m = 0; m < 8; ++m)
#pragma unroll
        for (int n = 0; n < 4; ++n)
#pragma unroll
            for (int e = 0; e < 4; ++e) acc[m][n][e] = 0.0f;

    bf16x8 a[2][4];       // [kk][mi] current QM quadrant
    bf16x8 b[2][2][2];    // [qn][kk][ni] both QN quadrants live

    const int base_f = (lane >> 4) * 2048 + (lane & 15) * 16;  // fhi*2048+frow*16

    // frag addr: abuf + kk*8192 + (QM*64 + mi*16)*16 + base_f
#define LDA(mi, kk, QM) (*(const bf16x8*)(abuf + (kk) * 8192 + (QM) * 1024 + (mi) * 256 + base_f))
#define LDB(ni, kk, QN) (*(const bf16x8*)(bbuf + (kk) * 8192 + (QN) * 512 + (ni) * 256 + base_f))

#define MFMA_Q(QM, QN) \
    __builtin_amdgcn_s_setprio(1); \
    _Pragma("unroll") for (int kk = 0; kk < 2; ++kk) \
    _Pragma("unroll") for (int mi = 0; mi < 4; ++mi) \
    _Pragma("unroll") for (int ni = 0; ni < 2; ++ni) \
        acc[(QM) * 4 + mi][(QN) * 2 + ni] = __builtin_amdgcn_mfma_f32_16x16x32_bf16( \
            a[kk][mi], b[QN][kk][ni], acc[(QM) * 4 + mi][(QN) * 2 + ni], 0, 0, 0); \
    __builtin_amdgcn_s_setprio(0);

#define MIDSYNC \
    __builtin_amdgcn_sched_barrier(0); \
    __builtin_amdgcn_s_barrier();

    for (int t = 0; t < NT; ++t) {
        const int   dbuf = (t & 1) << 16;
        const char* abuf = (const char*)lds + dbuf + wr * 16384;
        const char* bbuf = (const char*)lds + dbuf + 32768
                           + (wc >> 1) * 16384 + (wc & 1) * 1024;
        const int nslot = (dbuf ^ 65536);   // slot base of the other buffer

        // ---- P0: quadrant (0,0); reads a(QM0)+b(QN0) kk-first; stage A1(t+1)
        a[0][0] = LDA(0, 0, 0); a[0][1] = LDA(1, 0, 0);
        a[0][2] = LDA(2, 0, 0); a[0][3] = LDA(3, 0, 0);
        b[0][0][0] = LDB(0, 0, 0); b[0][0][1] = LDB(1, 0, 0);
        a[1][0] = LDA(0, 1, 0); a[1][1] = LDA(1, 1, 0);
        a[1][2] = LDA(2, 1, 0); a[1][3] = LDA(3, 1, 0);
        b[0][1][0] = LDB(0, 1, 0); b[0][1][1] = LDB(1, 1, 0);
        if (t + 1 < NT) STG(pA1, nslot + 16384);
        MIDSYNC;
        MFMA_Q(0, 0);
        __builtin_amdgcn_s_barrier();

        // ---- P1: quadrant (0,1); reads b(QN1)
        b[1][0][0] = LDB(0, 0, 1); b[1][0][1] = LDB(1, 0, 1);
        b[1][1][0] = LDB(0, 1, 1); b[1][1][1] = LDB(1, 1, 1);
        MIDSYNC;
        MFMA_Q(0, 1);
        __builtin_amdgcn_s_barrier();

        // ---- P2: quadrant (1,1); reads a(QM1); stage B0(t+2)
        a[0][0] = LDA(0, 0, 1); a[0][1] = LDA(1, 0, 1);
        a[0][2] = LDA(2, 0, 1); a[0][3] = LDA(3, 0, 1);
        a[1][0] = LDA(0, 1, 1); a[1][1] = LDA(1, 1, 1);
        a[1][2] = LDA(2, 1, 1); a[1][3] = LDA(3, 1, 1);
        if (t + 2 < NT) STG(pB0, dbuf + 32768);
        MIDSYNC;
        MFMA_Q(1, 1);
        __builtin_amdgcn_s_barrier();

        // ---- P3: quadrant (1,0); no reads; stage B1(t+2), A0(t+2)
        if (t + 2 < NT) { STG(pB1, dbuf + 32768 + 16384); STG(pA0, dbuf); }
        MFMA_Q(1, 0);
        // counted wait: tile t+1 fully landed (3 half-tiles = 6 loads in flight)
        if (t < NT - 2)       { asm volatile("s_waitcnt vmcnt(6)" ::: "memory"); }
        else if (t == NT - 2) { asm volatile("s_waitcnt vmcnt(0)" ::: "memory"); }
        __builtin_amdgcn_s_barrier();

        pA1 += BK; pB0 += BK; pB1 += BK; pA0 += BK;
    }

    // Epilogue: C write. row = base + (lane>>4)*4 + e, col = base + (lane&15)
    const int crow = bm0 + wr * 128 + (lane >> 4) * 4;
    const int ccol = bn0 + wc * 64 + (lane & 15);
#pragma unroll
    for (int mi = 0; mi < 8; ++mi)
#pragma unroll
        for (int ni = 0; ni < 4; ++ni) {
            float* cp = C + (size_t)(crow + mi * 16) * V_SZ + (ccol + ni * 16);
#pragma unroll
            for (int e = 0; e < 4; ++e)
                cp[(size_t)e * V_SZ] = acc[mi][ni][e];
        }
#undef STG
#undef LDA
#undef LDB
#undef MFMA_Q
#undef MIDSYNC
}

// ---------------------------------------------------------------------------
extern "C" void kernel_launch(void* const* d_in, const int* in_sizes, int n_in,
                              void* d_out, int out_size, void* d_ws, size_t ws_size,
                              hipStream_t stream) {
    const int*   ids        = (const int*)d_in[0];       // [B,S] = 8192
    const float* embeds     = (const float*)d_in[1];     // [B,S,D]
    const float* in_weight  = (const float*)d_in[2];     // [V,D]
    const float* out_weight = (const float*)d_in[3];     // [D,V]

    float* out_embedded = (float*)d_out;                       // M*D floats
    float* out_logits   = (float*)d_out + (size_t)M_SZ * D_SZ; // M*V floats

    // workspace: A bf16 [M][K] (16 MB) + Bt bf16 [V][K] (64 MB) = ~82 MB
    unsigned short* Abf  = (unsigned short*)d_ws;
    unsigned short* Btbf = Abf + (size_t)M_SZ * D_SZ;

    gather_rows<<<M_SZ, 256, 0, stream>>>(ids, in_weight, out_embedded);
    cast_f32_bf16<<<2048, 256, 0, stream>>>(embeds, Abf, M_SZ * D_SZ / 8);
    transpose_cast<<<dim3(V_SZ / 32, D_SZ / 32), 256, 0, stream>>>(out_weight, Btbf);
    gemm_bf16_8p<<<dim3((V_SZ / BN) * (M_SZ / BM)), 512, 0, stream>>>(Abf, Btbf, out_logits);
}

// Round 4
// 778.514 us; speedup vs baseline: 1.6592x; 1.1022x over previous
//
#include <hip/hip_runtime.h>
#include <hip/hip_bf16.h>
#include <stdint.h>

// Problem constants (from reference)
#define V_SZ 32000
#define D_SZ 1024          // = K
#define M_SZ 8192          // B*S = 4*2048

typedef __attribute__((ext_vector_type(8))) short bf16x8;
typedef __attribute__((ext_vector_type(4))) float f32x4;
typedef __attribute__((ext_vector_type(16))) float f32x16;

static __device__ __forceinline__ unsigned short f32_to_bf16_rne(float f) {
    union { float f; uint32_t u; } v; v.f = f;
    uint32_t u = v.u;
    uint32_t lsb = (u >> 16) & 1;
    u += 0x7fffu + lsb;
    return (unsigned short)(u >> 16);
}

// ---------------------------------------------------------------------------
// Kernel 1: embedding gather. One block per output row, float4 copy.
// Output is never re-read -> nontemporal stores.
__global__ void gather_rows(const int* __restrict__ ids,
                            const float* __restrict__ table,
                            float* __restrict__ out) {
    int row = blockIdx.x;
    int id  = ids[row];
    const f32x4* src = (const f32x4*)(table + (size_t)id * D_SZ);
    f32x4*       dst = (f32x4*)(out + (size_t)row * D_SZ);
    __builtin_nontemporal_store(src[threadIdx.x], &dst[threadIdx.x]);
}

// ---------------------------------------------------------------------------
// Kernel 2: cast embeds f32 -> bf16 (A matrix [M][K]), 8 elems/thread.
__global__ void cast_f32_bf16(const float* __restrict__ in,
                              unsigned short* __restrict__ out, int n8) {
    int i = blockIdx.x * blockDim.x + threadIdx.x;
    int stride = gridDim.x * blockDim.x;
    for (; i < n8; i += stride) {
        const float4* p = (const float4*)(in + (size_t)i * 8);
        float4 a = p[0], b = p[1];
        union { unsigned short s[8]; uint4 v; } r;
        r.s[0] = f32_to_bf16_rne(a.x); r.s[1] = f32_to_bf16_rne(a.y);
        r.s[2] = f32_to_bf16_rne(a.z); r.s[3] = f32_to_bf16_rne(a.w);
        r.s[4] = f32_to_bf16_rne(b.x); r.s[5] = f32_to_bf16_rne(b.y);
        r.s[6] = f32_to_bf16_rne(b.z); r.s[7] = f32_to_bf16_rne(b.w);
        ((uint4*)out)[i] = r.v;
    }
}

// ---------------------------------------------------------------------------
// Kernel 3: transpose+cast out_weight [K=1024][V=32000] f32 -> Bt [V][K] bf16.
__global__ void transpose_cast(const float* __restrict__ w,
                               unsigned short* __restrict__ bt) {
    __shared__ unsigned short tile[32][34];
    int n0 = blockIdx.x * 32;          // column block in V
    int k0 = blockIdx.y * 32;          // row block in K
    int r = threadIdx.x >> 5;          // 0..7
    int c = threadIdx.x & 31;          // 0..31
#pragma unroll
    for (int rr = 0; rr < 32; rr += 8) {
        float v = w[(size_t)(k0 + r + rr) * V_SZ + (n0 + c)];
        tile[c][r + rr] = f32_to_bf16_rne(v);
    }
    __syncthreads();
    int nl = threadIdx.x >> 3;         // 0..31
    int ks = threadIdx.x & 7;          // 0..7  (4 bf16 = 8B per thread)
    union { unsigned short s[4]; uint2 v; } r2;
#pragma unroll
    for (int j = 0; j < 4; ++j) r2.s[j] = tile[nl][ks * 4 + j];
    ((uint2*)(bt + (size_t)(n0 + nl) * D_SZ + k0))[ks] = r2.v;
}

// ---------------------------------------------------------------------------
// Kernel 4: bf16 GEMM, 256x256 tile, BK=64, 8 waves (2Mx4N), 4-phase/K-tile,
// 32x32x16 MFMA (2495 TF ceiling vs 2075 for 16x16x32).
// LDS 128 KiB: [dbuf][A|B][half]  half-tile = [8 hi][128 row][8 bf16] = 16KB.
// k-split layout: 0 bank conflicts measured, linear in global_load_lds order.
// C stores are nontemporal: C (1 GB, no reuse) must not evict A/B from L3.
#define BM 256
#define BN 256
#define BK 64
#define NT (D_SZ / BK)   // 16

static __device__ __forceinline__ void gload_lds16(const unsigned short* g, void* lds) {
    __builtin_amdgcn_global_load_lds(
        (const __attribute__((address_space(1))) void*)g,
        (__attribute__((address_space(3))) void*)lds,
        16, 0, 0);
}

__global__ __launch_bounds__(512, 2)
void gemm_bf16_8p(const unsigned short* __restrict__ A,
                  const unsigned short* __restrict__ Bt,
                  float* __restrict__ C) {
    __shared__ __align__(16) char lds[131072];

    const int tid  = threadIdx.x;
    const int lane = tid & 63;
    const int w    = tid >> 6;           // wave 0..7
    const int wr   = w >> 2;             // 0..1  (A half)
    const int wc   = w & 3;              // 0..3  (B: half = wc>>1, sub = wc&1)

    // XCD-aware swizzle (grid = 4000, %8==0 -> simple variant bijective)
    const int nwg = gridDim.x;
    const int cpx = nwg >> 3;            // 500
    const int bid = blockIdx.x;
    const int swz = (bid & 7) * cpx + (bid >> 3);
    const int bm0 = (swz & 31) * BM;     // bm fastest -> same-XCD blocks share B panel
    const int bn0 = (swz >> 5) * BN;

    // staging thread mapping: (hi0,row0) and (hi0+4,row0)
    const int hi0  = tid >> 7;           // 0..3
    const int row0 = tid & 127;          // 0..127
    const int dstO = hi0 * 2048 + row0 * 16;
    const unsigned short* gA = A  + (size_t)(bm0 + row0) * D_SZ + hi0 * 8;
    const unsigned short* gB = Bt + (size_t)(bn0 + row0) * D_SZ + hi0 * 8;

    // 2 x 16B direct-to-LDS per stage-half (512 thr * 32B = 16 KB)
#define STG(ptr, slotbase) do { \
    gload_lds16((ptr),      (char*)lds + (slotbase) + dstO); \
    gload_lds16((ptr) + 32, (char*)lds + (slotbase) + dstO + 8192); } while (0)

    // Prologue: tile 0 fully + tile 1 minus A1(1); wait oldest 8 (= tile 0).
    STG(gB,                           32768);
    STG(gB + (size_t)128 * D_SZ,      32768 + 16384);
    STG(gA,                           0);
    STG(gA + (size_t)128 * D_SZ,      16384);
    STG(gB + 64,                      65536 + 32768);
    STG(gB + (size_t)128 * D_SZ + 64, 65536 + 32768 + 16384);
    STG(gA + 64,                      65536);
    asm volatile("s_waitcnt vmcnt(6)" ::: "memory");
    __builtin_amdgcn_s_barrier();

    // running staging pointers (strength-reduced): A1 at tile t+1; rest at t+2
    const unsigned short* pA1 = gA + (size_t)128 * D_SZ + 64;
    const unsigned short* pB0 = gB + 128;
    const unsigned short* pB1 = gB + (size_t)128 * D_SZ + 128;
    const unsigned short* pA0 = gA + 128;

    // acc[mi][ni]: mi = 32-row group (0..3), ni = 32-col group (0..1)
    f32x16 acc[4][2];
#pragma unroll
    for (int m = 0; m < 4; ++m)
#pragma unroll
        for (int n = 0; n < 2; ++n)
#pragma unroll
            for (int e = 0; e < 16; ++e) acc[m][n][e] = 0.0f;

    bf16x8 a[2][4];       // [mi2][kk] current QM quadrant (2 row-groups x 4 k-slices)
    bf16x8 b[2][4];       // [qn][kk]  both QN quadrants live

    // 32x32x16 A/B frag: row/col = lane&31, k-group hi = kk*2 + (lane>>5)
    const int base_f = (lane >> 5) * 2048 + (lane & 31) * 16;

    // frag addr: buf + kk*4096 + (row-group)*512 + base_f
#define LDA(mi2, kk, QM) (*(const bf16x8*)(abuf + (kk) * 4096 + ((QM) * 2 + (mi2)) * 512 + base_f))
#define LDB(ni, kk)      (*(const bf16x8*)(bbuf + (kk) * 4096 + (ni) * 512 + base_f))

#define MFMA_Q(QM, QN) \
    __builtin_amdgcn_s_setprio(1); \
    _Pragma("unroll") for (int kk = 0; kk < 4; ++kk) \
    _Pragma("unroll") for (int mi2 = 0; mi2 < 2; ++mi2) \
        acc[(QM) * 2 + mi2][QN] = __builtin_amdgcn_mfma_f32_32x32x16_bf16( \
            a[mi2][kk], b[QN][kk], acc[(QM) * 2 + mi2][QN], 0, 0, 0); \
    __builtin_amdgcn_s_setprio(0);

#define MIDSYNC \
    __builtin_amdgcn_sched_barrier(0); \
    __builtin_amdgcn_s_barrier();

    for (int t = 0; t < NT; ++t) {
        const int   dbuf = (t & 1) << 16;
        const char* abuf = (const char*)lds + dbuf + wr * 16384;
        const char* bbuf = (const char*)lds + dbuf + 32768
                           + (wc >> 1) * 16384 + (wc & 1) * 1024;
        const int nslot = (dbuf ^ 65536);   // slot base of the other buffer

        // ---- P0: quadrant (QM0,QN0); stage A1(t+1)
        a[0][0] = LDA(0, 0, 0); a[0][1] = LDA(0, 1, 0);
        a[0][2] = LDA(0, 2, 0); a[0][3] = LDA(0, 3, 0);
        a[1][0] = LDA(1, 0, 0); a[1][1] = LDA(1, 1, 0);
        a[1][2] = LDA(1, 2, 0); a[1][3] = LDA(1, 3, 0);
        b[0][0] = LDB(0, 0); b[0][1] = LDB(0, 1);
        b[0][2] = LDB(0, 2); b[0][3] = LDB(0, 3);
        if (t + 1 < NT) STG(pA1, nslot + 16384);
        MIDSYNC;
        MFMA_Q(0, 0);
        __builtin_amdgcn_s_barrier();

        // ---- P1: quadrant (QM0,QN1); reads b(QN1)
        b[1][0] = LDB(1, 0); b[1][1] = LDB(1, 1);
        b[1][2] = LDB(1, 2); b[1][3] = LDB(1, 3);
        MIDSYNC;
        MFMA_Q(0, 1);
        __builtin_amdgcn_s_barrier();

        // ---- P2: quadrant (QM1,QN1); reads a(QM1); stage B0(t+2)
        a[0][0] = LDA(0, 0, 1); a[0][1] = LDA(0, 1, 1);
        a[0][2] = LDA(0, 2, 1); a[0][3] = LDA(0, 3, 1);
        a[1][0] = LDA(1, 0, 1); a[1][1] = LDA(1, 1, 1);
        a[1][2] = LDA(1, 2, 1); a[1][3] = LDA(1, 3, 1);
        if (t + 2 < NT) STG(pB0, dbuf + 32768);
        MIDSYNC;
        MFMA_Q(1, 1);
        __builtin_amdgcn_s_barrier();

        // ---- P3: quadrant (QM1,QN0); no reads; stage B1(t+2), A0(t+2)
        if (t + 2 < NT) { STG(pB1, dbuf + 32768 + 16384); STG(pA0, dbuf); }
        MFMA_Q(1, 0);
        // counted wait: tile t+1 fully landed (3 half-tiles = 6 loads in flight)
        if (t < NT - 2)       { asm volatile("s_waitcnt vmcnt(6)" ::: "memory"); }
        else if (t == NT - 2) { asm volatile("s_waitcnt vmcnt(0)" ::: "memory"); }
        __builtin_amdgcn_s_barrier();

        pA1 += BK; pB0 += BK; pB1 += BK; pA0 += BK;
    }

    // Epilogue. 32x32 C frag: col = lane&31, row = (r&3) + 8*(r>>2) + 4*(lane>>5).
    // Nontemporal: C is write-once, keep it out of L2/L3.
    const int crow = bm0 + wr * 128 + (lane >> 5) * 4;
    const int ccol = bn0 + wc * 64 + (lane & 31);
#pragma unroll
    for (int mi = 0; mi < 4; ++mi)
#pragma unroll
        for (int ni = 0; ni < 2; ++ni) {
            float* base = C + (size_t)(crow + mi * 32) * V_SZ + (ccol + ni * 32);
#pragma unroll
            for (int r = 0; r < 16; ++r) {
                int roff = (r & 3) + 8 * (r >> 2);
                __builtin_nontemporal_store(acc[mi][ni][r], base + (size_t)roff * V_SZ);
            }
        }
#undef STG
#undef LDA
#undef LDB
#undef MFMA_Q
#undef MIDSYNC
}

// ---------------------------------------------------------------------------
extern "C" void kernel_launch(void* const* d_in, const int* in_sizes, int n_in,
                              void* d_out, int out_size, void* d_ws, size_t ws_size,
                              hipStream_t stream) {
    const int*   ids        = (const int*)d_in[0];       // [B,S] = 8192
    const float* embeds     = (const float*)d_in[1];     // [B,S,D]
    const float* in_weight  = (const float*)d_in[2];     // [V,D]
    const float* out_weight = (const float*)d_in[3];     // [D,V]

    float* out_embedded = (float*)d_out;                       // M*D floats
    float* out_logits   = (float*)d_out + (size_t)M_SZ * D_SZ; // M*V floats

    // workspace: A bf16 [M][K] (16 MB) + Bt bf16 [V][K] (64 MB) = ~82 MB
    unsigned short* Abf  = (unsigned short*)d_ws;
    unsigned short* Btbf = Abf + (size_t)M_SZ * D_SZ;

    gather_rows<<<M_SZ, 256, 0, stream>>>(ids, in_weight, out_embedded);
    cast_f32_bf16<<<2048, 256, 0, stream>>>(embeds, Abf, M_SZ * D_SZ / 8);
    transpose_cast<<<dim3(V_SZ / 32, D_SZ / 32), 256, 0, stream>>>(out_weight, Btbf);
    gemm_bf16_8p<<<dim3((V_SZ / BN) * (M_SZ / BM)), 512, 0, stream>>>(Abf, Btbf, out_logits);
}

// Round 5
// 759.785 us; speedup vs baseline: 1.7001x; 1.0247x over previous
//
#include <hip/hip_runtime.h>
#include <hip/hip_bf16.h>
#include <stdint.h>

// Problem constants (from reference)
#define V_SZ 32000
#define D_SZ 1024          // = K
#define M_SZ 8192          // B*S = 4*2048

typedef __attribute__((ext_vector_type(8))) short bf16x8;
typedef __attribute__((ext_vector_type(4))) float f32x4;
typedef __attribute__((ext_vector_type(16))) float f32x16;

static __device__ __forceinline__ unsigned short f32_to_bf16_rne(float f) {
    union { float f; uint32_t u; } v; v.f = f;
    uint32_t u = v.u;
    uint32_t lsb = (u >> 16) & 1;
    u += 0x7fffu + lsb;
    return (unsigned short)(u >> 16);
}

// ---------------------------------------------------------------------------
// Kernel 1: embedding gather. One block per output row, float4 copy.
__global__ void gather_rows(const int* __restrict__ ids,
                            const float* __restrict__ table,
                            float* __restrict__ out) {
    int row = blockIdx.x;
    int id  = ids[row];
    const f32x4* src = (const f32x4*)(table + (size_t)id * D_SZ);
    f32x4*       dst = (f32x4*)(out + (size_t)row * D_SZ);
    __builtin_nontemporal_store(src[threadIdx.x], &dst[threadIdx.x]);
}

// ---------------------------------------------------------------------------
// Kernel 2: cast embeds f32 -> bf16 (A matrix [M][K]), 8 elems/thread.
__global__ void cast_f32_bf16(const float* __restrict__ in,
                              unsigned short* __restrict__ out, int n8) {
    int i = blockIdx.x * blockDim.x + threadIdx.x;
    int stride = gridDim.x * blockDim.x;
    for (; i < n8; i += stride) {
        const float4* p = (const float4*)(in + (size_t)i * 8);
        float4 a = p[0], b = p[1];
        union { unsigned short s[8]; uint4 v; } r;
        r.s[0] = f32_to_bf16_rne(a.x); r.s[1] = f32_to_bf16_rne(a.y);
        r.s[2] = f32_to_bf16_rne(a.z); r.s[3] = f32_to_bf16_rne(a.w);
        r.s[4] = f32_to_bf16_rne(b.x); r.s[5] = f32_to_bf16_rne(b.y);
        r.s[6] = f32_to_bf16_rne(b.z); r.s[7] = f32_to_bf16_rne(b.w);
        ((uint4*)out)[i] = r.v;
    }
}

// ---------------------------------------------------------------------------
// Kernel 3: transpose+cast out_weight [K=1024][V=32000] f32 -> Bt [V][K] bf16.
__global__ void transpose_cast(const float* __restrict__ w,
                               unsigned short* __restrict__ bt) {
    __shared__ unsigned short tile[32][34];
    int n0 = blockIdx.x * 32;          // column block in V
    int k0 = blockIdx.y * 32;          // row block in K
    int r = threadIdx.x >> 5;          // 0..7
    int c = threadIdx.x & 31;          // 0..31
#pragma unroll
    for (int rr = 0; rr < 32; rr += 8) {
        float v = w[(size_t)(k0 + r + rr) * V_SZ + (n0 + c)];
        tile[c][r + rr] = f32_to_bf16_rne(v);
    }
    __syncthreads();
    int nl = threadIdx.x >> 3;         // 0..31
    int ks = threadIdx.x & 7;          // 0..7  (4 bf16 = 8B per thread)
    union { unsigned short s[4]; uint2 v; } r2;
#pragma unroll
    for (int j = 0; j < 4; ++j) r2.s[j] = tile[nl][ks * 4 + j];
    ((uint2*)(bt + (size_t)(n0 + nl) * D_SZ + k0))[ks] = r2.v;
}

// ---------------------------------------------------------------------------
// Kernel 4: bf16 GEMM, 256x256 tile, BK=64, 8 waves (2Mx4N), 4-phase/K-tile,
// 32x32x16 MFMA. LDS 128 KiB double-buffered, k-split layout (0 conflicts).
// Block->tile mapping pins a 2 MB A-slice per XCD L2 (bm = xcd*4 + j&3) and
// sweeps bn in cross-XCD lockstep so L3 serves each B panel ~once to 8 XCDs.
#define BM 256
#define BN 256
#define BK 64
#define NT (D_SZ / BK)   // 16

static __device__ __forceinline__ void gload_lds16(const unsigned short* g, void* lds) {
    __builtin_amdgcn_global_load_lds(
        (const __attribute__((address_space(1))) void*)g,
        (__attribute__((address_space(3))) void*)lds,
        16, 0, 0);
}

__global__ __launch_bounds__(512, 2)
void gemm_bf16_8p(const unsigned short* __restrict__ A,
                  const unsigned short* __restrict__ Bt,
                  float* __restrict__ C) {
    __shared__ __align__(16) char lds[131072];

    const int tid  = threadIdx.x;
    const int lane = tid & 63;
    const int w    = tid >> 6;           // wave 0..7
    const int wr   = w >> 2;             // 0..1  (A half)
    const int wc   = w & 3;              // 0..3  (B: half = wc>>1, sub = wc&1)

    // XCD-pinned A-slice mapping (hardware round-robins bid across 8 XCDs):
    //   xcd = bid&7 owns bm tiles [4*xcd, 4*xcd+3]  -> A slice = 2 MB, L2-resident
    //   all XCDs sweep bn = j>>2 in lockstep -> B panel requests temporally
    //   clustered -> one HBM fetch serves all 8 XCDs via L3.
    const int bid = blockIdx.x;
    const int xcd = bid & 7;
    const int j   = bid >> 3;            // 0..499 = 4 bm x 125 bn (bijective)
    const int bm0 = (xcd * 4 + (j & 3)) * BM;
    const int bn0 = (j >> 2) * BN;

    // staging thread mapping: (hi0,row0) and (hi0+4,row0)
    const int hi0  = tid >> 7;           // 0..3
    const int row0 = tid & 127;          // 0..127
    const int dstO = hi0 * 2048 + row0 * 16;
    const unsigned short* gA = A  + (size_t)(bm0 + row0) * D_SZ + hi0 * 8;
    const unsigned short* gB = Bt + (size_t)(bn0 + row0) * D_SZ + hi0 * 8;

    // 2 x 16B direct-to-LDS per stage-half (512 thr * 32B = 16 KB)
#define STG(ptr, slotbase) do { \
    gload_lds16((ptr),      (char*)lds + (slotbase) + dstO); \
    gload_lds16((ptr) + 32, (char*)lds + (slotbase) + dstO + 8192); } while (0)

    // Prologue: tile 0 fully + tile 1 minus A1(1); wait oldest 8 (= tile 0).
    STG(gB,                           32768);
    STG(gB + (size_t)128 * D_SZ,      32768 + 16384);
    STG(gA,                           0);
    STG(gA + (size_t)128 * D_SZ,      16384);
    STG(gB + 64,                      65536 + 32768);
    STG(gB + (size_t)128 * D_SZ + 64, 65536 + 32768 + 16384);
    STG(gA + 64,                      65536);
    asm volatile("s_waitcnt vmcnt(6)" ::: "memory");
    __builtin_amdgcn_s_barrier();

    // running staging pointers (strength-reduced): A1 at tile t+1; rest at t+2
    const unsigned short* pA1 = gA + (size_t)128 * D_SZ + 64;
    const unsigned short* pB0 = gB + 128;
    const unsigned short* pB1 = gB + (size_t)128 * D_SZ + 128;
    const unsigned short* pA0 = gA + 128;

    // acc[mi][ni]: mi = 32-row group (0..3), ni = 32-col group (0..1)
    f32x16 acc[4][2];
#pragma unroll
    for (int m = 0; m < 4; ++m)
#pragma unroll
        for (int n = 0; n < 2; ++n)
#pragma unroll
            for (int e = 0; e < 16; ++e) acc[m][n][e] = 0.0f;

    bf16x8 a[2][4];       // [mi2][kk] current QM quadrant (2 row-groups x 4 k-slices)
    bf16x8 b[2][4];       // [qn][kk]  both QN quadrants live

    // 32x32x16 A/B frag: row/col = lane&31, k-group hi = kk*2 + (lane>>5)
    const int base_f = (lane >> 5) * 2048 + (lane & 31) * 16;

    // frag addr: buf + kk*4096 + (row-group)*512 + base_f
#define LDA(mi2, kk, QM) (*(const bf16x8*)(abuf + (kk) * 4096 + ((QM) * 2 + (mi2)) * 512 + base_f))
#define LDB(ni, kk)      (*(const bf16x8*)(bbuf + (kk) * 4096 + (ni) * 512 + base_f))

#define MFMA_Q(QM, QN) \
    __builtin_amdgcn_s_setprio(1); \
    _Pragma("unroll") for (int kk = 0; kk < 4; ++kk) \
    _Pragma("unroll") for (int mi2 = 0; mi2 < 2; ++mi2) \
        acc[(QM) * 2 + mi2][QN] = __builtin_amdgcn_mfma_f32_32x32x16_bf16( \
            a[mi2][kk], b[QN][kk], acc[(QM) * 2 + mi2][QN], 0, 0, 0); \
    __builtin_amdgcn_s_setprio(0);

#define MIDSYNC \
    __builtin_amdgcn_sched_barrier(0); \
    __builtin_amdgcn_s_barrier();

    for (int t = 0; t < NT; ++t) {
        const int   dbuf = (t & 1) << 16;
        const char* abuf = (const char*)lds + dbuf + wr * 16384;
        const char* bbuf = (const char*)lds + dbuf + 32768
                           + (wc >> 1) * 16384 + (wc & 1) * 1024;
        const int nslot = (dbuf ^ 65536);   // slot base of the other buffer

        // ---- P0: quadrant (QM0,QN0); stage A1(t+1)
        a[0][0] = LDA(0, 0, 0); a[0][1] = LDA(0, 1, 0);
        a[0][2] = LDA(0, 2, 0); a[0][3] = LDA(0, 3, 0);
        a[1][0] = LDA(1, 0, 0); a[1][1] = LDA(1, 1, 0);
        a[1][2] = LDA(1, 2, 0); a[1][3] = LDA(1, 3, 0);
        b[0][0] = LDB(0, 0); b[0][1] = LDB(0, 1);
        b[0][2] = LDB(0, 2); b[0][3] = LDB(0, 3);
        if (t + 1 < NT) STG(pA1, nslot + 16384);
        MIDSYNC;
        MFMA_Q(0, 0);
        __builtin_amdgcn_s_barrier();

        // ---- P1: quadrant (QM0,QN1); reads b(QN1)
        b[1][0] = LDB(1, 0); b[1][1] = LDB(1, 1);
        b[1][2] = LDB(1, 2); b[1][3] = LDB(1, 3);
        MIDSYNC;
        MFMA_Q(0, 1);
        __builtin_amdgcn_s_barrier();

        // ---- P2: quadrant (QM1,QN1); reads a(QM1); stage B0(t+2)
        a[0][0] = LDA(0, 0, 1); a[0][1] = LDA(0, 1, 1);
        a[0][2] = LDA(0, 2, 1); a[0][3] = LDA(0, 3, 1);
        a[1][0] = LDA(1, 0, 1); a[1][1] = LDA(1, 1, 1);
        a[1][2] = LDA(1, 2, 1); a[1][3] = LDA(1, 3, 1);
        if (t + 2 < NT) STG(pB0, dbuf + 32768);
        MIDSYNC;
        MFMA_Q(1, 1);
        __builtin_amdgcn_s_barrier();

        // ---- P3: quadrant (QM1,QN0); no reads; stage B1(t+2), A0(t+2)
        if (t + 2 < NT) { STG(pB1, dbuf + 32768 + 16384); STG(pA0, dbuf); }
        MFMA_Q(1, 0);
        // counted wait: tile t+1 fully landed (3 half-tiles = 6 loads in flight)
        if (t < NT - 2)       { asm volatile("s_waitcnt vmcnt(6)" ::: "memory"); }
        else if (t == NT - 2) { asm volatile("s_waitcnt vmcnt(0)" ::: "memory"); }
        __builtin_amdgcn_s_barrier();

        pA1 += BK; pB0 += BK; pB1 += BK; pA0 += BK;
    }

    // Epilogue. 32x32 C frag: col = lane&31, row = (r&3) + 8*(r>>2) + 4*(lane>>5).
    // Nontemporal: C is write-once.
    const int crow = bm0 + wr * 128 + (lane >> 5) * 4;
    const int ccol = bn0 + wc * 64 + (lane & 31);
#pragma unroll
    for (int mi = 0; mi < 4; ++mi)
#pragma unroll
        for (int ni = 0; ni < 2; ++ni) {
            float* base = C + (size_t)(crow + mi * 32) * V_SZ + (ccol + ni * 32);
#pragma unroll
            for (int r = 0; r < 16; ++r) {
                int roff = (r & 3) + 8 * (r >> 2);
                __builtin_nontemporal_store(acc[mi][ni][r], base + (size_t)roff * V_SZ);
            }
        }
#undef STG
#undef LDA
#undef LDB
#undef MFMA_Q
#undef MIDSYNC
}

// ---------------------------------------------------------------------------
extern "C" void kernel_launch(void* const* d_in, const int* in_sizes, int n_in,
                              void* d_out, int out_size, void* d_ws, size_t ws_size,
                              hipStream_t stream) {
    const int*   ids        = (const int*)d_in[0];       // [B,S] = 8192
    const float* embeds     = (const float*)d_in[1];     // [B,S,D]
    const float* in_weight  = (const float*)d_in[2];     // [V,D]
    const float* out_weight = (const float*)d_in[3];     // [D,V]

    float* out_embedded = (float*)d_out;                       // M*D floats
    float* out_logits   = (float*)d_out + (size_t)M_SZ * D_SZ; // M*V floats

    // workspace: A bf16 [M][K] (16 MB) + Bt bf16 [V][K] (64 MB) = ~82 MB
    unsigned short* Abf  = (unsigned short*)d_ws;
    unsigned short* Btbf = Abf + (size_t)M_SZ * D_SZ;

    gather_rows<<<M_SZ, 256, 0, stream>>>(ids, in_weight, out_embedded);
    cast_f32_bf16<<<2048, 256, 0, stream>>>(embeds, Abf, M_SZ * D_SZ / 8);
    transpose_cast<<<dim3(V_SZ / 32, D_SZ / 32), 256, 0, stream>>>(out_weight, Btbf);
    gemm_bf16_8p<<<dim3((V_SZ / BN) * (M_SZ / BM)), 512, 0, stream>>>(Abf, Btbf, out_logits);
}